// Round 10
// baseline (289.671 us; speedup 1.0000x reference)
//
#include <hip/hip_runtime.h>
#include <hip/hip_bf16.h>
#include <stdint.h>
#include <stddef.h>

#define SEQ 4096
#define DIN 1024
#define DQK 1024
#define DV  1024

typedef __bf16 bf16;
typedef __bf16 bf16x4 __attribute__((ext_vector_type(4)));
typedef __bf16 bf16x8 __attribute__((ext_vector_type(8)));
typedef float  f32x4  __attribute__((ext_vector_type(4)));

// ---------------- K0a: elementwise split fp32 -> bf16 hi/lo ----------------
__global__ __launch_bounds__(256) void split_f32(const float* __restrict__ in,
                                                 bf16* __restrict__ hi,
                                                 bf16* __restrict__ lo, int n4) {
  int i = blockIdx.x * 256 + threadIdx.x;
  if (i >= n4) return;
  const float4 v = ((const float4*)in)[i];
  float a[4] = {v.x, v.y, v.z, v.w};
  bf16x4 h, l;
#pragma unroll
  for (int t = 0; t < 4; ++t) {
    bf16 hh = (bf16)a[t];
    h[t] = hh;
    l[t] = (bf16)(a[t] - (float)hh);
  }
  ((bf16x4*)hi)[i] = h;
  ((bf16x4*)lo)[i] = l;
}

// ------------ K0b: all three W (K x N fp32) -> W^T (N x K bf16) fused -------
__global__ __launch_bounds__(256) void wtrans_all(
    const float* __restrict__ Wq, const float* __restrict__ Wk,
    const float* __restrict__ Wv, bf16* __restrict__ wqh,
    bf16* __restrict__ wql, bf16* __restrict__ wkh, bf16* __restrict__ wkl,
    bf16* __restrict__ wvt) {
  __shared__ float t[32][33];
  const int g = blockIdx.x >> 10;  // 0=Wq 1=Wk 2=Wv
  const int bid = blockIdx.x & 1023;
  const float* W = (g == 0) ? Wq : (g == 1) ? Wk : Wv;
  bf16* outH = (g == 0) ? wqh : (g == 1) ? wkh : wvt;
  bf16* outL = (g == 0) ? wql : wkl;  // unused when g==2
  const bool do_split = (g < 2);
  const int bx = bid & 31;   // n-tile
  const int by = bid >> 5;   // k-tile
  const int tx = threadIdx.x & 31;
  const int ty = threadIdx.x >> 5;  // 0..7
#pragma unroll
  for (int r = 0; r < 32; r += 8)
    t[ty + r][tx] = W[(size_t)(by * 32 + ty + r) * DQK + bx * 32 + tx];
  __syncthreads();
#pragma unroll
  for (int r = 0; r < 32; r += 8) {
    float v = t[tx][ty + r];  // = W[by*32+tx][bx*32+ty+r]
    size_t o = (size_t)(bx * 32 + ty + r) * DIN + by * 32 + tx;
    bf16 h = (bf16)v;
    outH[o] = h;
    if (do_split) outL[o] = (bf16)(v - (float)h);
  }
}

// ---------------- global -> LDS staging of one 128x32 bf16 tile -------------
__device__ __forceinline__ void stage_tile(const bf16* __restrict__ g, int ld,
                                           int row0, int k0, bf16* lds,
                                           int wid, int lane) {
#pragma unroll
  for (int c = 0; c < 2; ++c) {
    const int q = wid * 2 + c;  // chunk 0..7: rows [q*16, q*16+16)
    const bf16* src =
        g + (size_t)(row0 + q * 16 + (lane >> 2)) * ld + k0 + (lane & 3) * 8;
    __builtin_amdgcn_global_load_lds(
        (const __attribute__((address_space(1))) void*)src,
        (__attribute__((address_space(3))) void*)(lds + q * 512), 16, 0, 0);
  }
}

__device__ __forceinline__ bf16x8 ldsfrag(const bf16* s, int rbase, int lane) {
  return *(const bf16x8*)&s[(rbase + (lane & 15)) * 32 + ((lane >> 4) * 8)];
}

// ---------------- projection GEMM body (m97 pattern, 128x128 tile) ----------
template <bool SPLIT>
__device__ __forceinline__ void proj_body(
    const bf16* __restrict__ Agh, const bf16* __restrict__ Agl,
    const bf16* __restrict__ Bgh, const bf16* __restrict__ Bgl,
    bf16* __restrict__ outH, bf16* __restrict__ outL, int bm, int bn, int ldo,
    bf16* sAh, bf16* sBh, bf16* sAl, bf16* sBl) {
  const int wid = threadIdx.x >> 6;
  const int lane = threadIdx.x & 63;
  const int wr = (wid >> 1) * 64;
  const int wc = (wid & 1) * 64;

  f32x4 acc[4][4];
#pragma unroll
  for (int i = 0; i < 4; ++i)
#pragma unroll
    for (int j = 0; j < 4; ++j) acc[i][j] = (f32x4)(0.0f);

  for (int kt = 0; kt < DIN / 32; ++kt) {
    const int k0 = kt * 32;
    __syncthreads();
    stage_tile(Agh, DIN, bm * 128, k0, sAh, wid, lane);
    stage_tile(Bgh, DIN, bn * 128, k0, sBh, wid, lane);
    if (SPLIT) {
      stage_tile(Agl, DIN, bm * 128, k0, sAl, wid, lane);
      stage_tile(Bgl, DIN, bn * 128, k0, sBl, wid, lane);
    }
    __syncthreads();

    bf16x8 ah[4], bh[4];
#pragma unroll
    for (int i = 0; i < 4; ++i) ah[i] = ldsfrag(sAh, wr + i * 16, lane);
#pragma unroll
    for (int j = 0; j < 4; ++j) bh[j] = ldsfrag(sBh, wc + j * 16, lane);
#pragma unroll
    for (int i = 0; i < 4; ++i)
#pragma unroll
      for (int j = 0; j < 4; ++j)
        acc[i][j] = __builtin_amdgcn_mfma_f32_16x16x32_bf16(ah[i], bh[j],
                                                            acc[i][j], 0, 0, 0);
    if (SPLIT) {
      bf16x8 bl[4];
#pragma unroll
      for (int j = 0; j < 4; ++j) bl[j] = ldsfrag(sBl, wc + j * 16, lane);
#pragma unroll
      for (int i = 0; i < 4; ++i)
#pragma unroll
        for (int j = 0; j < 4; ++j)
          acc[i][j] = __builtin_amdgcn_mfma_f32_16x16x32_bf16(
              ah[i], bl[j], acc[i][j], 0, 0, 0);
      bf16x8 al[4];
#pragma unroll
      for (int i = 0; i < 4; ++i) al[i] = ldsfrag(sAl, wr + i * 16, lane);
#pragma unroll
      for (int i = 0; i < 4; ++i)
#pragma unroll
        for (int j = 0; j < 4; ++j)
          acc[i][j] = __builtin_amdgcn_mfma_f32_16x16x32_bf16(
              al[i], bh[j], acc[i][j], 0, 0, 0);
    }
  }

  const int r0 = bm * 128 + wr + ((lane >> 4) * 4);
  const int c0 = bn * 128 + wc + (lane & 15);
#pragma unroll
  for (int i = 0; i < 4; ++i)
#pragma unroll
    for (int j = 0; j < 4; ++j)
#pragma unroll
      for (int r = 0; r < 4; ++r) {
        const size_t o = (size_t)(r0 + i * 16 + r) * ldo + (c0 + j * 16);
        const float v = acc[i][j][r];
        bf16 h = (bf16)v;
        outH[o] = h;
        if (SPLIT) outL[o] = (bf16)(v - (float)h);
      }
}

// ---------------- K1: fused Q/K (split) + V^T (plain) projections -----------
__global__ __launch_bounds__(256, 2) void fused_proj(
    const bf16* __restrict__ xh, const bf16* __restrict__ xl,
    const bf16* __restrict__ wqh, const bf16* __restrict__ wql,
    const bf16* __restrict__ wkh, const bf16* __restrict__ wkl,
    const bf16* __restrict__ wvt, bf16* __restrict__ qh, bf16* __restrict__ ql,
    bf16* __restrict__ kh, bf16* __restrict__ kl, bf16* __restrict__ vt) {
  __shared__ bf16 sAh[128 * 32];
  __shared__ bf16 sBh[128 * 32];
  __shared__ bf16 sAl[128 * 32];
  __shared__ bf16 sBl[128 * 32];
  const int b = blockIdx.x;
  if (b < 256) {
    proj_body<true>(xh, xl, wqh, wql, qh, ql, b >> 3, b & 7, DQK, sAh, sBh, sAl,
                    sBl);
  } else if (b < 512) {
    const int bb = b - 256;
    proj_body<true>(xh, xl, wkh, wkl, kh, kl, bb >> 3, bb & 7, DQK, sAh, sBh,
                    sAl, sBl);
  } else {
    const int bb = b - 512;
    // V^T[dv][seq] = sum_k WvT[dv][k] * x[seq][k]
    proj_body<false>(wvt, nullptr, xh, nullptr, vt, nullptr, bb >> 5, bb & 31,
                     SEQ, sAh, sBh, sAl, sBl);
  }
}

// ---------------- K2: causal score tiles, SINGLE bf16 pass, fp32 out --------
__global__ __launch_bounds__(256, 2) void score1(const bf16* __restrict__ qh,
                                                 const bf16* __restrict__ kh,
                                                 float* __restrict__ S) {
  __shared__ bf16 sA[128 * 32];
  __shared__ bf16 sB[128 * 32];
  const int t = blockIdx.x;
  int bi = (int)((sqrtf(8.0f * (float)t + 1.0f) - 1.0f) * 0.5f);
  while ((bi + 1) * (bi + 2) / 2 <= t) ++bi;
  while (bi * (bi + 1) / 2 > t) --bi;
  const int bm = bi;
  const int bn = t - bi * (bi + 1) / 2;

  const int wid = threadIdx.x >> 6;
  const int lane = threadIdx.x & 63;
  const int wr = (wid >> 1) * 64;
  const int wc = (wid & 1) * 64;

  f32x4 acc[4][4];
#pragma unroll
  for (int i = 0; i < 4; ++i)
#pragma unroll
    for (int j = 0; j < 4; ++j) acc[i][j] = (f32x4)(0.0f);

  for (int kt = 0; kt < DQK / 32; ++kt) {
    const int k0 = kt * 32;
    __syncthreads();
    stage_tile(qh, DQK, bm * 128, k0, sA, wid, lane);
    stage_tile(kh, DQK, bn * 128, k0, sB, wid, lane);
    __syncthreads();
    bf16x8 a[4], b[4];
#pragma unroll
    for (int i = 0; i < 4; ++i) a[i] = ldsfrag(sA, wr + i * 16, lane);
#pragma unroll
    for (int j = 0; j < 4; ++j) b[j] = ldsfrag(sB, wc + j * 16, lane);
#pragma unroll
    for (int i = 0; i < 4; ++i)
#pragma unroll
      for (int j = 0; j < 4; ++j)
        acc[i][j] = __builtin_amdgcn_mfma_f32_16x16x32_bf16(a[i], b[j],
                                                            acc[i][j], 0, 0, 0);
  }

  const int r0 = bm * 128 + wr + ((lane >> 4) * 4);
  const int c0 = bn * 128 + wc + (lane & 15);
#pragma unroll
  for (int i = 0; i < 4; ++i)
#pragma unroll
    for (int j = 0; j < 4; ++j)
#pragma unroll
      for (int r = 0; r < 4; ++r)
        S[(size_t)(r0 + i * 16 + r) * SEQ + (c0 + j * 16)] = acc[i][j][r];
}

// ---------------- K3 v2: softmax + batched exact fixup, LDS-light -----------
// One wave per row, 4 waves/block, ~20 KB LDS (qf row + candidate list) ->
// high occupancy. Scans: (1) approx max m0 (read S); (2) collect candidates
// (v >= m0-1024) into LDS list; batched exact dots: 8 candidates at a time,
// 8 lanes each (128B-coalesced K reads, shfl_xor(1,2,4) reduce), corrected
// scores written back into S (fp32) and true max m tracked; __threadfence()
// (L1 invalidate - scans below re-read lines cached before correction);
// (3) sum of exp((s-m)/32) over corrected S; (4) write P bf16 in place
// (reads precede writes wave-wide per iter; strictly ascending => safe).
__global__ __launch_bounds__(256) void softmax_fixup(
    float* __restrict__ S, const bf16* __restrict__ qh,
    const bf16* __restrict__ ql, const bf16* __restrict__ kh,
    const bf16* __restrict__ kl) {
  __shared__ __align__(16) float qf[4][1024];
  __shared__ int lists[4][256];
  __shared__ int cnts[4];
  const int wid = threadIdx.x >> 6;
  const int lane = threadIdx.x & 63;
  const int row = blockIdx.x * 4 + wid;
  const int len = row + 1;
  const int ext = ((row >> 7) + 1) << 7;
  float* srow = S + (size_t)row * SEQ;

  if (lane == 0) cnts[wid] = 0;
  {  // build fp32 q row in LDS (16 elems/lane)
    const size_t base = (size_t)row * DQK + lane * 16;
    bf16x8 h0 = *(const bf16x8*)(qh + base);
    bf16x8 h1 = *(const bf16x8*)(qh + base + 8);
    bf16x8 l0 = *(const bf16x8*)(ql + base);
    bf16x8 l1 = *(const bf16x8*)(ql + base + 8);
    float* dst = &qf[wid][lane * 16];
#pragma unroll
    for (int t = 0; t < 8; ++t) {
      dst[t] = (float)h0[t] + (float)l0[t];
      dst[8 + t] = (float)h1[t] + (float)l1[t];
    }
  }
  __syncthreads();

  // scan1: approx max
  float m0 = -3.0e38f;
  for (int j = lane * 4; j < len; j += 256) {
    float4 v = *(const float4*)(srow + j);
    if (j + 0 < len) m0 = fmaxf(m0, v.x);
    if (j + 1 < len) m0 = fmaxf(m0, v.y);
    if (j + 2 < len) m0 = fmaxf(m0, v.z);
    if (j + 3 < len) m0 = fmaxf(m0, v.w);
  }
#pragma unroll
  for (int o = 32; o > 0; o >>= 1) m0 = fmaxf(m0, __shfl_xor(m0, o));

  // scan2: collect band candidates into per-wave LDS list
  const float T = m0 - 1024.0f;
  for (int j = lane * 4; j < len; j += 256) {
    float4 v = *(const float4*)(srow + j);
    float va[4] = {v.x, v.y, v.z, v.w};
#pragma unroll
    for (int t = 0; t < 4; ++t) {
      if (j + t < len && va[t] >= T) {
        int p = atomicAdd(&cnts[wid], 1);
        if (p < 256) lists[wid][p] = j + t;
      }
    }
  }
  int cnt = cnts[wid];  // per-wave LDS ops are in-order
  if (cnt > 256) cnt = 256;

  // batched exact dots: 8 candidates x 8 lanes each
  const int cslot = lane >> 3;  // candidate within batch
  const int seg = lane & 7;     // 128-elem segment base selector
  const float* qfr = qf[wid];
  float m = -3.0e38f;
  for (int b = 0; b < cnt; b += 8) {
    const int idx = b + cslot;
    const bool valid = idx < cnt;
    const int jj = valid ? lists[wid][idx] : 0;
    float d = valid ? 0.f : -3.0e38f;
    if (valid) {
      const bf16* khr = kh + (size_t)jj * DQK;
      const bf16* klr = kl + (size_t)jj * DQK;
#pragma unroll 4
      for (int g = 0; g < 16; ++g) {
        const int e0 = g * 64 + seg * 8;  // lanes seg=0..7 -> 128B contiguous
        bf16x8 h = *(const bf16x8*)(khr + e0);
        bf16x8 l = *(const bf16x8*)(klr + e0);
#pragma unroll
        for (int t = 0; t < 8; ++t)
          d += qfr[e0 + t] * ((float)h[t] + (float)l[t]);
      }
    }
#pragma unroll
    for (int o = 1; o < 8; o <<= 1) {
      float od = __shfl_xor(d, o);
      d = valid ? d + od : d;  // invalid lanes keep -inf sentinel
    }
    if (valid && seg == 0) srow[jj] = d;  // corrected score -> S
    m = fmaxf(m, d);
  }
#pragma unroll
  for (int o = 32; o > 0; o >>= 1) m = fmaxf(m, __shfl_xor(m, o));

  __threadfence();  // drain correction stores + invalidate L1 before re-read

  // scan3: sum of exp over corrected S
  float lsum = 0.f;
  for (int j = lane * 4; j < len; j += 256) {
    float4 v = *(const float4*)(srow + j);
    lsum += (j + 0 < len) ? __expf((v.x - m) * 0.03125f) : 0.f;
    lsum += (j + 1 < len) ? __expf((v.y - m) * 0.03125f) : 0.f;
    lsum += (j + 2 < len) ? __expf((v.z - m) * 0.03125f) : 0.f;
    lsum += (j + 3 < len) ? __expf((v.w - m) * 0.03125f) : 0.f;
  }
#pragma unroll
  for (int o = 32; o > 0; o >>= 1) lsum += __shfl_xor(lsum, o);
  const float inv = 1.0f / lsum;

  // scan4: write P bf16 in place, zero-filled to tile boundary
  bf16* prow = (bf16*)srow;
  for (int j = lane * 4; j < ext; j += 256) {
    float4 v = *(const float4*)(srow + j);  // loads precede stores (wave-wide)
    float va[4] = {v.x, v.y, v.z, v.w};
    bf16x4 o4;
#pragma unroll
    for (int t = 0; t < 4; ++t) {
      const float e =
          (j + t < len) ? __expf((va[t] - m) * 0.03125f) * inv : 0.f;
      o4[t] = (bf16)e;
    }
    *(bf16x4*)(prow + j) = o4;
  }
}

// ---------------- K4: O = P V, balanced split-K over causal extent ----------
__global__ __launch_bounds__(256, 2) void pv_kernel(const bf16* __restrict__ P,
                                                    const bf16* __restrict__ vt,
                                                    float* __restrict__ out,
                                                    float* __restrict__ part) {
  __shared__ bf16 sA[128 * 32];
  __shared__ bf16 sB[128 * 32];
  const int g = blockIdx.x >> 3;
  const int bn = blockIdx.x & 7;
  int bm, slice;
  if (g < 8) {
    bm = g;
    slice = 0;
  } else if (g < 24) {
    const int i = g - 8;
    bm = 8 + (i >> 1);
    slice = i & 1;
  } else if (g < 48) {
    const int i = g - 24;
    bm = 16 + i / 3;
    slice = i % 3;
  } else {
    const int i = g - 48;
    bm = 24 + (i >> 2);
    slice = i & 3;
  }
  const int ks0 = slice * 32;
  const int kend = (bm + 1) * 4;
  const int nk = (ks0 + 32 < kend) ? ks0 + 32 : kend;

  const int wid = threadIdx.x >> 6;
  const int lane = threadIdx.x & 63;
  const int wr = (wid >> 1) * 64;
  const int wc = (wid & 1) * 64;

  f32x4 acc[4][4];
#pragma unroll
  for (int i = 0; i < 4; ++i)
#pragma unroll
    for (int j = 0; j < 4; ++j) acc[i][j] = (f32x4)(0.0f);

  for (int kt = ks0; kt < nk; ++kt) {
    const int k0 = kt * 32;
    __syncthreads();
    stage_tile(P, 2 * SEQ, bm * 128, k0, sA, wid, lane);  // ld = 8192
    stage_tile(vt, SEQ, bn * 128, k0, sB, wid, lane);
    __syncthreads();
    bf16x8 a[4], b[4];
#pragma unroll
    for (int i = 0; i < 4; ++i) a[i] = ldsfrag(sA, wr + i * 16, lane);
#pragma unroll
    for (int j = 0; j < 4; ++j) b[j] = ldsfrag(sB, wc + j * 16, lane);
#pragma unroll
    for (int i = 0; i < 4; ++i)
#pragma unroll
      for (int j = 0; j < 4; ++j)
        acc[i][j] = __builtin_amdgcn_mfma_f32_16x16x32_bf16(a[i], b[j],
                                                            acc[i][j], 0, 0, 0);
  }

  float* dst;
  int rbase;
  if (slice == 0) {
    dst = out;
    rbase = 0;
  } else if (slice == 1) {
    dst = part;
    rbase = 1024;
  } else if (slice == 2) {
    dst = part + 3145728;
    rbase = 2048;
  } else {
    dst = part + 5242880;
    rbase = 3072;
  }
  const int r0 = bm * 128 + wr + ((lane >> 4) * 4);
  const int c0 = bn * 128 + wc + (lane & 15);
#pragma unroll
  for (int i = 0; i < 4; ++i)
#pragma unroll
    for (int j = 0; j < 4; ++j)
#pragma unroll
      for (int r = 0; r < 4; ++r)
        dst[(size_t)(r0 + i * 16 + r - rbase) * DV + (c0 + j * 16)] =
            acc[i][j][r];
}

// ---------------- K5: add split-K partial slices into out -------------------
__global__ __launch_bounds__(256) void pv_reduce(const float* __restrict__ part,
                                                 float* __restrict__ out) {
  const int idx = blockIdx.x * 256 + threadIdx.x;
  const int r = 1024 + (idx >> 8);
  const int c4 = (idx & 255) * 4;
  const size_t o = (size_t)r * DV + c4;
  float4 acc = *(float4*)&out[o];
  const float4 p1 = *(const float4*)&part[(size_t)(r - 1024) * DV + c4];
  acc.x += p1.x; acc.y += p1.y; acc.z += p1.z; acc.w += p1.w;
  if (r >= 2048) {
    const float4 p2 =
        *(const float4*)&part[3145728 + (size_t)(r - 2048) * DV + c4];
    acc.x += p2.x; acc.y += p2.y; acc.z += p2.z; acc.w += p2.w;
  }
  if (r >= 3072) {
    const float4 p3 =
        *(const float4*)&part[5242880 + (size_t)(r - 3072) * DV + c4];
    acc.x += p3.x; acc.y += p3.y; acc.z += p3.z; acc.w += p3.w;
  }
  *(float4*)&out[o] = acc;
}

// ---------------- launch ----------------
extern "C" void kernel_launch(void* const* d_in, const int* in_sizes, int n_in,
                              void* d_out, int out_size, void* d_ws,
                              size_t ws_size, hipStream_t stream) {
  const float* x = (const float*)d_in[0];
  const float* Wq = (const float*)d_in[1];
  const float* Wk = (const float*)d_in[2];
  const float* Wv = (const float*)d_in[3];
  float* out = (float*)d_out;
  char* ws = (char*)d_ws;

  const size_t MB = 1024 * 1024;
  const size_t OFF_QH = 0, OFF_QL = 8 * MB, OFF_KH = 16 * MB, OFF_KL = 24 * MB;
  const size_t OFF_PART = 0;  // 24 MB fp32 tight-packed (aliases dead Q/K)
  const size_t OFF_VT = 32 * MB;
  const size_t OFF_S = 40 * MB;
  const size_t OFF_XH = 40 * MB, OFF_XL = 48 * MB;
  const size_t OFF_WQH = 56 * MB, OFF_WQL = 58 * MB;
  const size_t OFF_WKH = 60 * MB, OFF_WKL = 62 * MB, OFF_WVT = 64 * MB;
  const size_t NEEDED = 104 * MB;
  if (ws_size < NEEDED) return;

  bf16* qh = (bf16*)(ws + OFF_QH);
  bf16* ql = (bf16*)(ws + OFF_QL);
  bf16* kh = (bf16*)(ws + OFF_KH);
  bf16* kl = (bf16*)(ws + OFF_KL);
  float* part = (float*)(ws + OFF_PART);
  bf16* vt = (bf16*)(ws + OFF_VT);
  float* S = (float*)(ws + OFF_S);
  bf16* xh = (bf16*)(ws + OFF_XH);
  bf16* xl = (bf16*)(ws + OFF_XL);
  bf16* wqh = (bf16*)(ws + OFF_WQH);
  bf16* wql = (bf16*)(ws + OFF_WQL);
  bf16* wkh = (bf16*)(ws + OFF_WKH);
  bf16* wkl = (bf16*)(ws + OFF_WKL);
  bf16* wvt = (bf16*)(ws + OFF_WVT);

  // K0: conversions
  split_f32<<<(SEQ * DIN / 4 + 255) / 256, 256, 0, stream>>>(x, xh, xl,
                                                             SEQ * DIN / 4);
  wtrans_all<<<3072, 256, 0, stream>>>(Wq, Wk, Wv, wqh, wql, wkh, wkl, wvt);

  // K1: fused projections (Q split, K split, V^T plain) — 768 blocks
  fused_proj<<<768, 256, 0, stream>>>(xh, xl, wqh, wql, wkh, wkl, wvt, qh, ql,
                                      kh, kl, vt);

  // K2: causal scores, single bf16 pass -> S fp32
  score1<<<(SEQ / 128) * (SEQ / 128 + 1) / 2, 256, 0, stream>>>(qh, kh, S);

  // K3: softmax with batched exact fixup; writes P bf16 in-place into S
  softmax_fixup<<<SEQ / 4, 256, 0, stream>>>(S, qh, ql, kh, kl);

  // K4: O = P V, balanced split-K (640 blocks)
  pv_kernel<<<640, 256, 0, stream>>>((const bf16*)S, vt, out, part);

  // K5: fold partial slices into out (rows >= 1024)
  pv_reduce<<<(SEQ - 1024) * DV / 4 / 256, 256, 0, stream>>>(part, out);
}

// Round 11
// 215.373 us; speedup vs baseline: 1.3450x; 1.3450x over previous
//
#include <hip/hip_runtime.h>
#include <hip/hip_bf16.h>
#include <stdint.h>
#include <stddef.h>

#define SEQ 4096
#define DIN 1024
#define DQK 1024
#define DV  1024

typedef __bf16 bf16;
typedef __bf16 bf16x4 __attribute__((ext_vector_type(4)));
typedef __bf16 bf16x8 __attribute__((ext_vector_type(8)));
typedef float  f32x4  __attribute__((ext_vector_type(4)));

// ---------------- K0a: elementwise split fp32 -> bf16 hi/lo ----------------
__global__ __launch_bounds__(256) void split_f32(const float* __restrict__ in,
                                                 bf16* __restrict__ hi,
                                                 bf16* __restrict__ lo, int n4) {
  int i = blockIdx.x * 256 + threadIdx.x;
  if (i >= n4) return;
  const float4 v = ((const float4*)in)[i];
  float a[4] = {v.x, v.y, v.z, v.w};
  bf16x4 h, l;
#pragma unroll
  for (int t = 0; t < 4; ++t) {
    bf16 hh = (bf16)a[t];
    h[t] = hh;
    l[t] = (bf16)(a[t] - (float)hh);
  }
  ((bf16x4*)hi)[i] = h;
  ((bf16x4*)lo)[i] = l;
}

// ------------ K0b: all three W (K x N fp32) -> W^T (N x K bf16) fused -------
__global__ __launch_bounds__(256) void wtrans_all(
    const float* __restrict__ Wq, const float* __restrict__ Wk,
    const float* __restrict__ Wv, bf16* __restrict__ wqh,
    bf16* __restrict__ wql, bf16* __restrict__ wkh, bf16* __restrict__ wkl,
    bf16* __restrict__ wvt) {
  __shared__ float t[32][33];
  const int g = blockIdx.x >> 10;  // 0=Wq 1=Wk 2=Wv
  const int bid = blockIdx.x & 1023;
  const float* W = (g == 0) ? Wq : (g == 1) ? Wk : Wv;
  bf16* outH = (g == 0) ? wqh : (g == 1) ? wkh : wvt;
  bf16* outL = (g == 0) ? wql : wkl;  // unused when g==2
  const bool do_split = (g < 2);
  const int bx = bid & 31;   // n-tile
  const int by = bid >> 5;   // k-tile
  const int tx = threadIdx.x & 31;
  const int ty = threadIdx.x >> 5;  // 0..7
#pragma unroll
  for (int r = 0; r < 32; r += 8)
    t[ty + r][tx] = W[(size_t)(by * 32 + ty + r) * DQK + bx * 32 + tx];
  __syncthreads();
#pragma unroll
  for (int r = 0; r < 32; r += 8) {
    float v = t[tx][ty + r];  // = W[by*32+tx][bx*32+ty+r]
    size_t o = (size_t)(bx * 32 + ty + r) * DIN + by * 32 + tx;
    bf16 h = (bf16)v;
    outH[o] = h;
    if (do_split) outL[o] = (bf16)(v - (float)h);
  }
}

// ---------------- global -> LDS staging of one 128x32 bf16 tile -------------
__device__ __forceinline__ void stage_tile(const bf16* __restrict__ g, int ld,
                                           int row0, int k0, bf16* lds,
                                           int wid, int lane) {
#pragma unroll
  for (int c = 0; c < 2; ++c) {
    const int q = wid * 2 + c;  // chunk 0..7: rows [q*16, q*16+16)
    const bf16* src =
        g + (size_t)(row0 + q * 16 + (lane >> 2)) * ld + k0 + (lane & 3) * 8;
    __builtin_amdgcn_global_load_lds(
        (const __attribute__((address_space(1))) void*)src,
        (__attribute__((address_space(3))) void*)(lds + q * 512), 16, 0, 0);
  }
}

__device__ __forceinline__ bf16x8 ldsfrag(const bf16* s, int rbase, int lane) {
  return *(const bf16x8*)&s[(rbase + (lane & 15)) * 32 + ((lane >> 4) * 8)];
}

// ---------------- projection GEMM body (m97 pattern, 128x128 tile) ----------
template <bool SPLIT>
__device__ __forceinline__ void proj_body(
    const bf16* __restrict__ Agh, const bf16* __restrict__ Agl,
    const bf16* __restrict__ Bgh, const bf16* __restrict__ Bgl,
    bf16* __restrict__ outH, bf16* __restrict__ outL, int bm, int bn, int ldo,
    bf16* sAh, bf16* sBh, bf16* sAl, bf16* sBl) {
  const int wid = threadIdx.x >> 6;
  const int lane = threadIdx.x & 63;
  const int wr = (wid >> 1) * 64;
  const int wc = (wid & 1) * 64;

  f32x4 acc[4][4];
#pragma unroll
  for (int i = 0; i < 4; ++i)
#pragma unroll
    for (int j = 0; j < 4; ++j) acc[i][j] = (f32x4)(0.0f);

  for (int kt = 0; kt < DIN / 32; ++kt) {
    const int k0 = kt * 32;
    __syncthreads();
    stage_tile(Agh, DIN, bm * 128, k0, sAh, wid, lane);
    stage_tile(Bgh, DIN, bn * 128, k0, sBh, wid, lane);
    if (SPLIT) {
      stage_tile(Agl, DIN, bm * 128, k0, sAl, wid, lane);
      stage_tile(Bgl, DIN, bn * 128, k0, sBl, wid, lane);
    }
    __syncthreads();

    bf16x8 ah[4], bh[4];
#pragma unroll
    for (int i = 0; i < 4; ++i) ah[i] = ldsfrag(sAh, wr + i * 16, lane);
#pragma unroll
    for (int j = 0; j < 4; ++j) bh[j] = ldsfrag(sBh, wc + j * 16, lane);
#pragma unroll
    for (int i = 0; i < 4; ++i)
#pragma unroll
      for (int j = 0; j < 4; ++j)
        acc[i][j] = __builtin_amdgcn_mfma_f32_16x16x32_bf16(ah[i], bh[j],
                                                            acc[i][j], 0, 0, 0);
    if (SPLIT) {
      bf16x8 bl[4];
#pragma unroll
      for (int j = 0; j < 4; ++j) bl[j] = ldsfrag(sBl, wc + j * 16, lane);
#pragma unroll
      for (int i = 0; i < 4; ++i)
#pragma unroll
        for (int j = 0; j < 4; ++j)
          acc[i][j] = __builtin_amdgcn_mfma_f32_16x16x32_bf16(
              ah[i], bl[j], acc[i][j], 0, 0, 0);
      bf16x8 al[4];
#pragma unroll
      for (int i = 0; i < 4; ++i) al[i] = ldsfrag(sAl, wr + i * 16, lane);
#pragma unroll
      for (int i = 0; i < 4; ++i)
#pragma unroll
        for (int j = 0; j < 4; ++j)
          acc[i][j] = __builtin_amdgcn_mfma_f32_16x16x32_bf16(
              al[i], bh[j], acc[i][j], 0, 0, 0);
    }
  }

  const int r0 = bm * 128 + wr + ((lane >> 4) * 4);
  const int c0 = bn * 128 + wc + (lane & 15);
#pragma unroll
  for (int i = 0; i < 4; ++i)
#pragma unroll
    for (int j = 0; j < 4; ++j)
#pragma unroll
      for (int r = 0; r < 4; ++r) {
        const size_t o = (size_t)(r0 + i * 16 + r) * ldo + (c0 + j * 16);
        const float v = acc[i][j][r];
        bf16 h = (bf16)v;
        outH[o] = h;
        if (SPLIT) outL[o] = (bf16)(v - (float)h);
      }
}

// ---------------- K1: fused Q/K (split) + V^T (plain) projections -----------
__global__ __launch_bounds__(256, 2) void fused_proj(
    const bf16* __restrict__ xh, const bf16* __restrict__ xl,
    const bf16* __restrict__ wqh, const bf16* __restrict__ wql,
    const bf16* __restrict__ wkh, const bf16* __restrict__ wkl,
    const bf16* __restrict__ wvt, bf16* __restrict__ qh, bf16* __restrict__ ql,
    bf16* __restrict__ kh, bf16* __restrict__ kl, bf16* __restrict__ vt) {
  __shared__ bf16 sAh[128 * 32];
  __shared__ bf16 sBh[128 * 32];
  __shared__ bf16 sAl[128 * 32];
  __shared__ bf16 sBl[128 * 32];
  const int b = blockIdx.x;
  if (b < 256) {
    proj_body<true>(xh, xl, wqh, wql, qh, ql, b >> 3, b & 7, DQK, sAh, sBh, sAl,
                    sBl);
  } else if (b < 512) {
    const int bb = b - 256;
    proj_body<true>(xh, xl, wkh, wkl, kh, kl, bb >> 3, bb & 7, DQK, sAh, sBh,
                    sAl, sBl);
  } else {
    const int bb = b - 512;
    // V^T[dv][seq] = sum_k WvT[dv][k] * x[seq][k]
    proj_body<false>(wvt, nullptr, xh, nullptr, vt, nullptr, bb >> 5, bb & 31,
                     SEQ, sAh, sBh, sAl, sBl);
  }
}

// ---------------- K2: causal score tiles, SINGLE bf16 pass, fp32 out --------
__global__ __launch_bounds__(256, 2) void score1(const bf16* __restrict__ qh,
                                                 const bf16* __restrict__ kh,
                                                 float* __restrict__ S) {
  __shared__ bf16 sA[128 * 32];
  __shared__ bf16 sB[128 * 32];
  const int t = blockIdx.x;
  int bi = (int)((sqrtf(8.0f * (float)t + 1.0f) - 1.0f) * 0.5f);
  while ((bi + 1) * (bi + 2) / 2 <= t) ++bi;
  while (bi * (bi + 1) / 2 > t) --bi;
  const int bm = bi;
  const int bn = t - bi * (bi + 1) / 2;

  const int wid = threadIdx.x >> 6;
  const int lane = threadIdx.x & 63;
  const int wr = (wid >> 1) * 64;
  const int wc = (wid & 1) * 64;

  f32x4 acc[4][4];
#pragma unroll
  for (int i = 0; i < 4; ++i)
#pragma unroll
    for (int j = 0; j < 4; ++j) acc[i][j] = (f32x4)(0.0f);

  for (int kt = 0; kt < DQK / 32; ++kt) {
    const int k0 = kt * 32;
    __syncthreads();
    stage_tile(qh, DQK, bm * 128, k0, sA, wid, lane);
    stage_tile(kh, DQK, bn * 128, k0, sB, wid, lane);
    __syncthreads();
    bf16x8 a[4], b[4];
#pragma unroll
    for (int i = 0; i < 4; ++i) a[i] = ldsfrag(sA, wr + i * 16, lane);
#pragma unroll
    for (int j = 0; j < 4; ++j) b[j] = ldsfrag(sB, wc + j * 16, lane);
#pragma unroll
    for (int i = 0; i < 4; ++i)
#pragma unroll
      for (int j = 0; j < 4; ++j)
        acc[i][j] = __builtin_amdgcn_mfma_f32_16x16x32_bf16(a[i], b[j],
                                                            acc[i][j], 0, 0, 0);
  }

  const int r0 = bm * 128 + wr + ((lane >> 4) * 4);
  const int c0 = bn * 128 + wc + (lane & 15);
#pragma unroll
  for (int i = 0; i < 4; ++i)
#pragma unroll
    for (int j = 0; j < 4; ++j)
#pragma unroll
      for (int r = 0; r < 4; ++r)
        S[(size_t)(r0 + i * 16 + r) * SEQ + (c0 + j * 16)] = acc[i][j][r];
}

// ---------------- K3 v3: softmax + BATCHED exact fixup (v1 structure) -------
// v1 structure (fp32 row in LDS, corrections to LDS, no fences/global writes;
// 64KB LDS -> 2 blocks/CU) with the serial candidate loop replaced by
// batched-8: per 64-chunk ballot, 8 lane-groups of 8 process 8 candidates
// concurrently. Q/K read from global (Q row is L1-hot after first batch).
__global__ __launch_bounds__(256) void softmax_fixup(
    float* __restrict__ S, const bf16* __restrict__ qh,
    const bf16* __restrict__ ql, const bf16* __restrict__ kh,
    const bf16* __restrict__ kl) {
  __shared__ __align__(16) float rb[4][4096];
  const int wid = threadIdx.x >> 6;
  const int lane = threadIdx.x & 63;
  const int row = blockIdx.x * 4 + wid;
  const int len = row + 1;
  const int ext = ((row >> 7) + 1) << 7;
  float* srow = S + (size_t)row * SEQ;
  float* rbw = rb[wid];

  // pass A: stage row into LDS, approx max
  float m0 = -3.0e38f;
  for (int j = lane * 4; j < len; j += 256) {
    float4 v = *(const float4*)(srow + j);
    *(float4*)&rbw[j] = v;
    if (j + 0 < len) m0 = fmaxf(m0, v.x);
    if (j + 1 < len) m0 = fmaxf(m0, v.y);
    if (j + 2 < len) m0 = fmaxf(m0, v.z);
    if (j + 3 < len) m0 = fmaxf(m0, v.w);
  }
#pragma unroll
  for (int o = 32; o > 0; o >>= 1) m0 = fmaxf(m0, __shfl_xor(m0, o));
  __syncthreads();

  // pass B: batched exact recompute of band candidates
  const float T = m0 - 1024.0f;
  const int cslot = lane >> 3;  // candidate slot within batch (0..7)
  const int seg = lane & 7;     // K-segment selector within group
  const bf16* qhr = qh + (size_t)row * DQK;
  const bf16* qlr = ql + (size_t)row * DQK;
  float m = -3.0e38f;  // true row max (max entry is always a candidate)
  for (int base = 0; base < len; base += 64) {
    const int j = base + lane;
    const bool cand = (j < len) && (rbw[j] >= T);
    unsigned long long mask = __ballot(cand);
    while (mask) {
      // lane's candidate = cslot-th set bit of (wave-uniform) mask
      unsigned long long mm = mask;
#pragma unroll
      for (int t = 0; t < 7; ++t) mm = (t < cslot) ? (mm & (mm - 1)) : mm;
      const bool valid = (mm != 0ull);
      const int jj = base + (valid ? (int)__builtin_ctzll(mm) : 0);
      float d = 0.f;
      if (valid) {
        const bf16* khr = kh + (size_t)jj * DQK;
        const bf16* klr = kl + (size_t)jj * DQK;
        float d0 = 0.f, d1 = 0.f;
#pragma unroll 2
        for (int g = 0; g < 16; ++g) {
          const int e0 = g * 64 + seg * 8;  // group's 8 lanes: 128B contiguous
          bf16x8 h = *(const bf16x8*)(khr + e0);
          bf16x8 l = *(const bf16x8*)(klr + e0);
          bf16x8 a = *(const bf16x8*)(qhr + e0);
          bf16x8 b = *(const bf16x8*)(qlr + e0);
#pragma unroll
          for (int t = 0; t < 8; ++t) {
            const float qv = (float)a[t] + (float)b[t];
            const float kv = (float)h[t] + (float)l[t];
            if (t & 1) d1 += qv * kv; else d0 += qv * kv;
          }
        }
        d = d0 + d1;
      }
#pragma unroll
      for (int o = 1; o < 8; o <<= 1) d += __shfl_xor(d, o);  // group sum
      if (valid) {
        m = fmaxf(m, d);
        if (seg == 0) rbw[jj] = d;  // corrected score -> LDS
      }
#pragma unroll
      for (int t = 0; t < 8; ++t) mask &= mask - 1;  // drop 8 processed bits
    }
  }
#pragma unroll
  for (int o = 32; o > 0; o >>= 1) m = fmaxf(m, __shfl_xor(m, o));
  __syncthreads();

  // pass C: e = exp((s-m)/32) into LDS, sum
  float lsum = 0.f;
  for (int j = lane * 4; j < len; j += 256) {
    float4 v = *(float4*)&rbw[j];
    float4 e;
    e.x = (j + 0 < len) ? __expf((v.x - m) * 0.03125f) : 0.f;
    e.y = (j + 1 < len) ? __expf((v.y - m) * 0.03125f) : 0.f;
    e.z = (j + 2 < len) ? __expf((v.z - m) * 0.03125f) : 0.f;
    e.w = (j + 3 < len) ? __expf((v.w - m) * 0.03125f) : 0.f;
    *(float4*)&rbw[j] = e;
    lsum += e.x + e.y + e.z + e.w;
  }
#pragma unroll
  for (int o = 32; o > 0; o >>= 1) lsum += __shfl_xor(lsum, o);
  const float inv = 1.0f / lsum;
  __syncthreads();

  // pass D: write P bf16 in place (row-owned slot), zero-fill to ext
  bf16* prow = (bf16*)srow;
  for (int j = lane * 8; j < ext; j += 512) {
    bf16x8 o8;
#pragma unroll
    for (int t = 0; t < 8; ++t) {
      const int jj = j + t;
      const float v = (jj < len) ? rbw[jj] * inv : 0.f;
      o8[t] = (bf16)v;
    }
    *(bf16x8*)(prow + j) = o8;
  }
}

// ---------------- K4: O = P V, balanced split-K over causal extent ----------
__global__ __launch_bounds__(256, 2) void pv_kernel(const bf16* __restrict__ P,
                                                    const bf16* __restrict__ vt,
                                                    float* __restrict__ out,
                                                    float* __restrict__ part) {
  __shared__ bf16 sA[128 * 32];
  __shared__ bf16 sB[128 * 32];
  const int g = blockIdx.x >> 3;
  const int bn = blockIdx.x & 7;
  int bm, slice;
  if (g < 8) {
    bm = g;
    slice = 0;
  } else if (g < 24) {
    const int i = g - 8;
    bm = 8 + (i >> 1);
    slice = i & 1;
  } else if (g < 48) {
    const int i = g - 24;
    bm = 16 + i / 3;
    slice = i % 3;
  } else {
    const int i = g - 48;
    bm = 24 + (i >> 2);
    slice = i & 3;
  }
  const int ks0 = slice * 32;
  const int kend = (bm + 1) * 4;
  const int nk = (ks0 + 32 < kend) ? ks0 + 32 : kend;

  const int wid = threadIdx.x >> 6;
  const int lane = threadIdx.x & 63;
  const int wr = (wid >> 1) * 64;
  const int wc = (wid & 1) * 64;

  f32x4 acc[4][4];
#pragma unroll
  for (int i = 0; i < 4; ++i)
#pragma unroll
    for (int j = 0; j < 4; ++j) acc[i][j] = (f32x4)(0.0f);

  for (int kt = ks0; kt < nk; ++kt) {
    const int k0 = kt * 32;
    __syncthreads();
    stage_tile(P, 2 * SEQ, bm * 128, k0, sA, wid, lane);  // ld = 8192
    stage_tile(vt, SEQ, bn * 128, k0, sB, wid, lane);
    __syncthreads();
    bf16x8 a[4], b[4];
#pragma unroll
    for (int i = 0; i < 4; ++i) a[i] = ldsfrag(sA, wr + i * 16, lane);
#pragma unroll
    for (int j = 0; j < 4; ++j) b[j] = ldsfrag(sB, wc + j * 16, lane);
#pragma unroll
    for (int i = 0; i < 4; ++i)
#pragma unroll
      for (int j = 0; j < 4; ++j)
        acc[i][j] = __builtin_amdgcn_mfma_f32_16x16x32_bf16(a[i], b[j],
                                                            acc[i][j], 0, 0, 0);
  }

  float* dst;
  int rbase;
  if (slice == 0) {
    dst = out;
    rbase = 0;
  } else if (slice == 1) {
    dst = part;
    rbase = 1024;
  } else if (slice == 2) {
    dst = part + 3145728;
    rbase = 2048;
  } else {
    dst = part + 5242880;
    rbase = 3072;
  }
  const int r0 = bm * 128 + wr + ((lane >> 4) * 4);
  const int c0 = bn * 128 + wc + (lane & 15);
#pragma unroll
  for (int i = 0; i < 4; ++i)
#pragma unroll
    for (int j = 0; j < 4; ++j)
#pragma unroll
      for (int r = 0; r < 4; ++r)
        dst[(size_t)(r0 + i * 16 + r - rbase) * DV + (c0 + j * 16)] =
            acc[i][j][r];
}

// ---------------- K5: add split-K partial slices into out -------------------
__global__ __launch_bounds__(256) void pv_reduce(const float* __restrict__ part,
                                                 float* __restrict__ out) {
  const int idx = blockIdx.x * 256 + threadIdx.x;
  const int r = 1024 + (idx >> 8);
  const int c4 = (idx & 255) * 4;
  const size_t o = (size_t)r * DV + c4;
  float4 acc = *(float4*)&out[o];
  const float4 p1 = *(const float4*)&part[(size_t)(r - 1024) * DV + c4];
  acc.x += p1.x; acc.y += p1.y; acc.z += p1.z; acc.w += p1.w;
  if (r >= 2048) {
    const float4 p2 =
        *(const float4*)&part[3145728 + (size_t)(r - 2048) * DV + c4];
    acc.x += p2.x; acc.y += p2.y; acc.z += p2.z; acc.w += p2.w;
  }
  if (r >= 3072) {
    const float4 p3 =
        *(const float4*)&part[5242880 + (size_t)(r - 3072) * DV + c4];
    acc.x += p3.x; acc.y += p3.y; acc.z += p3.z; acc.w += p3.w;
  }
  *(float4*)&out[o] = acc;
}

// ---------------- launch ----------------
extern "C" void kernel_launch(void* const* d_in, const int* in_sizes, int n_in,
                              void* d_out, int out_size, void* d_ws,
                              size_t ws_size, hipStream_t stream) {
  const float* x = (const float*)d_in[0];
  const float* Wq = (const float*)d_in[1];
  const float* Wk = (const float*)d_in[2];
  const float* Wv = (const float*)d_in[3];
  float* out = (float*)d_out;
  char* ws = (char*)d_ws;

  const size_t MB = 1024 * 1024;
  const size_t OFF_QH = 0, OFF_QL = 8 * MB, OFF_KH = 16 * MB, OFF_KL = 24 * MB;
  const size_t OFF_PART = 0;  // 24 MB fp32 tight-packed (aliases dead Q/K)
  const size_t OFF_VT = 32 * MB;
  const size_t OFF_S = 40 * MB;
  const size_t OFF_XH = 40 * MB, OFF_XL = 48 * MB;
  const size_t OFF_WQH = 56 * MB, OFF_WQL = 58 * MB;
  const size_t OFF_WKH = 60 * MB, OFF_WKL = 62 * MB, OFF_WVT = 64 * MB;
  const size_t NEEDED = 104 * MB;
  if (ws_size < NEEDED) return;

  bf16* qh = (bf16*)(ws + OFF_QH);
  bf16* ql = (bf16*)(ws + OFF_QL);
  bf16* kh = (bf16*)(ws + OFF_KH);
  bf16* kl = (bf16*)(ws + OFF_KL);
  float* part = (float*)(ws + OFF_PART);
  bf16* vt = (bf16*)(ws + OFF_VT);
  float* S = (float*)(ws + OFF_S);
  bf16* xh = (bf16*)(ws + OFF_XH);
  bf16* xl = (bf16*)(ws + OFF_XL);
  bf16* wqh = (bf16*)(ws + OFF_WQH);
  bf16* wql = (bf16*)(ws + OFF_WQL);
  bf16* wkh = (bf16*)(ws + OFF_WKH);
  bf16* wkl = (bf16*)(ws + OFF_WKL);
  bf16* wvt = (bf16*)(ws + OFF_WVT);

  // K0: conversions
  split_f32<<<(SEQ * DIN / 4 + 255) / 256, 256, 0, stream>>>(x, xh, xl,
                                                             SEQ * DIN / 4);
  wtrans_all<<<3072, 256, 0, stream>>>(Wq, Wk, Wv, wqh, wql, wkh, wkl, wvt);

  // K1: fused projections (Q split, K split, V^T plain) — 768 blocks
  fused_proj<<<768, 256, 0, stream>>>(xh, xl, wqh, wql, wkh, wkl, wvt, qh, ql,
                                      kh, kl, vt);

  // K2: causal scores, single bf16 pass -> S fp32
  score1<<<(SEQ / 128) * (SEQ / 128 + 1) / 2, 256, 0, stream>>>(qh, kh, S);

  // K3: softmax with batched exact fixup; writes P bf16 in-place into S
  softmax_fixup<<<SEQ / 4, 256, 0, stream>>>(S, qh, ql, kh, kl);

  // K4: O = P V, balanced split-K (640 blocks)
  pv_kernel<<<640, 256, 0, stream>>>((const bf16*)S, vt, out, part);

  // K5: fold partial slices into out (rows >= 1024)
  pv_reduce<<<(SEQ - 1024) * DV / 4 / 256, 256, 0, stream>>>(part, out);
}

// Round 12
// 185.703 us; speedup vs baseline: 1.5599x; 1.1598x over previous
//
#include <hip/hip_runtime.h>
#include <hip/hip_bf16.h>
#include <stdint.h>
#include <stddef.h>

#define SEQ 4096
#define DIN 1024
#define DQK 1024
#define DV  1024

typedef __bf16 bf16;
typedef __bf16 bf16x4 __attribute__((ext_vector_type(4)));
typedef __bf16 bf16x8 __attribute__((ext_vector_type(8)));
typedef float  f32x4  __attribute__((ext_vector_type(4)));

// ---------------- K0a: elementwise split fp32 -> bf16 hi/lo ----------------
__global__ __launch_bounds__(256) void split_f32(const float* __restrict__ in,
                                                 bf16* __restrict__ hi,
                                                 bf16* __restrict__ lo, int n4) {
  int i = blockIdx.x * 256 + threadIdx.x;
  if (i >= n4) return;
  const float4 v = ((const float4*)in)[i];
  float a[4] = {v.x, v.y, v.z, v.w};
  bf16x4 h, l;
#pragma unroll
  for (int t = 0; t < 4; ++t) {
    bf16 hh = (bf16)a[t];
    h[t] = hh;
    l[t] = (bf16)(a[t] - (float)hh);
  }
  ((bf16x4*)hi)[i] = h;
  ((bf16x4*)lo)[i] = l;
}

// ------------ K0b: all three W (K x N fp32) -> W^T (N x K bf16) fused -------
__global__ __launch_bounds__(256) void wtrans_all(
    const float* __restrict__ Wq, const float* __restrict__ Wk,
    const float* __restrict__ Wv, bf16* __restrict__ wqh,
    bf16* __restrict__ wql, bf16* __restrict__ wkh, bf16* __restrict__ wkl,
    bf16* __restrict__ wvt) {
  __shared__ float t[32][33];
  const int g = blockIdx.x >> 10;  // 0=Wq 1=Wk 2=Wv
  const int bid = blockIdx.x & 1023;
  const float* W = (g == 0) ? Wq : (g == 1) ? Wk : Wv;
  bf16* outH = (g == 0) ? wqh : (g == 1) ? wkh : wvt;
  bf16* outL = (g == 0) ? wql : wkl;  // unused when g==2
  const bool do_split = (g < 2);
  const int bx = bid & 31;   // n-tile
  const int by = bid >> 5;   // k-tile
  const int tx = threadIdx.x & 31;
  const int ty = threadIdx.x >> 5;  // 0..7
#pragma unroll
  for (int r = 0; r < 32; r += 8)
    t[ty + r][tx] = W[(size_t)(by * 32 + ty + r) * DQK + bx * 32 + tx];
  __syncthreads();
#pragma unroll
  for (int r = 0; r < 32; r += 8) {
    float v = t[tx][ty + r];  // = W[by*32+tx][bx*32+ty+r]
    size_t o = (size_t)(bx * 32 + ty + r) * DIN + by * 32 + tx;
    bf16 h = (bf16)v;
    outH[o] = h;
    if (do_split) outL[o] = (bf16)(v - (float)h);
  }
}

// ---------------- global -> LDS staging of one 128x32 bf16 tile -------------
__device__ __forceinline__ void stage_tile(const bf16* __restrict__ g, int ld,
                                           int row0, int k0, bf16* lds,
                                           int wid, int lane) {
#pragma unroll
  for (int c = 0; c < 2; ++c) {
    const int q = wid * 2 + c;  // chunk 0..7: rows [q*16, q*16+16)
    const bf16* src =
        g + (size_t)(row0 + q * 16 + (lane >> 2)) * ld + k0 + (lane & 3) * 8;
    __builtin_amdgcn_global_load_lds(
        (const __attribute__((address_space(1))) void*)src,
        (__attribute__((address_space(3))) void*)(lds + q * 512), 16, 0, 0);
  }
}

__device__ __forceinline__ bf16x8 ldsfrag(const bf16* s, int rbase, int lane) {
  return *(const bf16x8*)&s[(rbase + (lane & 15)) * 32 + ((lane >> 4) * 8)];
}

// ---------------- projection GEMM body (m97 pattern, 128x128 tile) ----------
template <bool SPLIT>
__device__ __forceinline__ void proj_body(
    const bf16* __restrict__ Agh, const bf16* __restrict__ Agl,
    const bf16* __restrict__ Bgh, const bf16* __restrict__ Bgl,
    bf16* __restrict__ outH, bf16* __restrict__ outL, int bm, int bn, int ldo,
    bf16* sAh, bf16* sBh, bf16* sAl, bf16* sBl) {
  const int wid = threadIdx.x >> 6;
  const int lane = threadIdx.x & 63;
  const int wr = (wid >> 1) * 64;
  const int wc = (wid & 1) * 64;

  f32x4 acc[4][4];
#pragma unroll
  for (int i = 0; i < 4; ++i)
#pragma unroll
    for (int j = 0; j < 4; ++j) acc[i][j] = (f32x4)(0.0f);

  for (int kt = 0; kt < DIN / 32; ++kt) {
    const int k0 = kt * 32;
    __syncthreads();
    stage_tile(Agh, DIN, bm * 128, k0, sAh, wid, lane);
    stage_tile(Bgh, DIN, bn * 128, k0, sBh, wid, lane);
    if (SPLIT) {
      stage_tile(Agl, DIN, bm * 128, k0, sAl, wid, lane);
      stage_tile(Bgl, DIN, bn * 128, k0, sBl, wid, lane);
    }
    __syncthreads();

    bf16x8 ah[4], bh[4];
#pragma unroll
    for (int i = 0; i < 4; ++i) ah[i] = ldsfrag(sAh, wr + i * 16, lane);
#pragma unroll
    for (int j = 0; j < 4; ++j) bh[j] = ldsfrag(sBh, wc + j * 16, lane);
#pragma unroll
    for (int i = 0; i < 4; ++i)
#pragma unroll
      for (int j = 0; j < 4; ++j)
        acc[i][j] = __builtin_amdgcn_mfma_f32_16x16x32_bf16(ah[i], bh[j],
                                                            acc[i][j], 0, 0, 0);
    if (SPLIT) {
      bf16x8 bl[4];
#pragma unroll
      for (int j = 0; j < 4; ++j) bl[j] = ldsfrag(sBl, wc + j * 16, lane);
#pragma unroll
      for (int i = 0; i < 4; ++i)
#pragma unroll
        for (int j = 0; j < 4; ++j)
          acc[i][j] = __builtin_amdgcn_mfma_f32_16x16x32_bf16(
              ah[i], bl[j], acc[i][j], 0, 0, 0);
      bf16x8 al[4];
#pragma unroll
      for (int i = 0; i < 4; ++i) al[i] = ldsfrag(sAl, wr + i * 16, lane);
#pragma unroll
      for (int i = 0; i < 4; ++i)
#pragma unroll
        for (int j = 0; j < 4; ++j)
          acc[i][j] = __builtin_amdgcn_mfma_f32_16x16x32_bf16(
              al[i], bh[j], acc[i][j], 0, 0, 0);
    }
  }

  const int r0 = bm * 128 + wr + ((lane >> 4) * 4);
  const int c0 = bn * 128 + wc + (lane & 15);
#pragma unroll
  for (int i = 0; i < 4; ++i)
#pragma unroll
    for (int j = 0; j < 4; ++j)
#pragma unroll
      for (int r = 0; r < 4; ++r) {
        const size_t o = (size_t)(r0 + i * 16 + r) * ldo + (c0 + j * 16);
        const float v = acc[i][j][r];
        bf16 h = (bf16)v;
        outH[o] = h;
        if (SPLIT) outL[o] = (bf16)(v - (float)h);
      }
}

// ---------------- K1: fused Q/K (split) + V^T (plain) projections -----------
__global__ __launch_bounds__(256, 2) void fused_proj(
    const bf16* __restrict__ xh, const bf16* __restrict__ xl,
    const bf16* __restrict__ wqh, const bf16* __restrict__ wql,
    const bf16* __restrict__ wkh, const bf16* __restrict__ wkl,
    const bf16* __restrict__ wvt, bf16* __restrict__ qh, bf16* __restrict__ ql,
    bf16* __restrict__ kh, bf16* __restrict__ kl, bf16* __restrict__ vt) {
  __shared__ bf16 sAh[128 * 32];
  __shared__ bf16 sBh[128 * 32];
  __shared__ bf16 sAl[128 * 32];
  __shared__ bf16 sBl[128 * 32];
  const int b = blockIdx.x;
  if (b < 256) {
    proj_body<true>(xh, xl, wqh, wql, qh, ql, b >> 3, b & 7, DQK, sAh, sBh, sAl,
                    sBl);
  } else if (b < 512) {
    const int bb = b - 256;
    proj_body<true>(xh, xl, wkh, wkl, kh, kl, bb >> 3, bb & 7, DQK, sAh, sBh,
                    sAl, sBl);
  } else {
    const int bb = b - 512;
    // V^T[dv][seq] = sum_k WvT[dv][k] * x[seq][k]
    proj_body<false>(wvt, nullptr, xh, nullptr, vt, nullptr, bb >> 5, bb & 31,
                     SEQ, sAh, sBh, sAl, sBl);
  }
}

// ---------------- K2: causal score tiles, SINGLE bf16 pass, fp32 out --------
__global__ __launch_bounds__(256, 2) void score1(const bf16* __restrict__ qh,
                                                 const bf16* __restrict__ kh,
                                                 float* __restrict__ S) {
  __shared__ bf16 sA[128 * 32];
  __shared__ bf16 sB[128 * 32];
  const int t = blockIdx.x;
  int bi = (int)((sqrtf(8.0f * (float)t + 1.0f) - 1.0f) * 0.5f);
  while ((bi + 1) * (bi + 2) / 2 <= t) ++bi;
  while (bi * (bi + 1) / 2 > t) --bi;
  const int bm = bi;
  const int bn = t - bi * (bi + 1) / 2;

  const int wid = threadIdx.x >> 6;
  const int lane = threadIdx.x & 63;
  const int wr = (wid >> 1) * 64;
  const int wc = (wid & 1) * 64;

  f32x4 acc[4][4];
#pragma unroll
  for (int i = 0; i < 4; ++i)
#pragma unroll
    for (int j = 0; j < 4; ++j) acc[i][j] = (f32x4)(0.0f);

  for (int kt = 0; kt < DQK / 32; ++kt) {
    const int k0 = kt * 32;
    __syncthreads();
    stage_tile(qh, DQK, bm * 128, k0, sA, wid, lane);
    stage_tile(kh, DQK, bn * 128, k0, sB, wid, lane);
    __syncthreads();
    bf16x8 a[4], b[4];
#pragma unroll
    for (int i = 0; i < 4; ++i) a[i] = ldsfrag(sA, wr + i * 16, lane);
#pragma unroll
    for (int j = 0; j < 4; ++j) b[j] = ldsfrag(sB, wc + j * 16, lane);
#pragma unroll
    for (int i = 0; i < 4; ++i)
#pragma unroll
      for (int j = 0; j < 4; ++j)
        acc[i][j] = __builtin_amdgcn_mfma_f32_16x16x32_bf16(a[i], b[j],
                                                            acc[i][j], 0, 0, 0);
  }

  const int r0 = bm * 128 + wr + ((lane >> 4) * 4);
  const int c0 = bn * 128 + wc + (lane & 15);
#pragma unroll
  for (int i = 0; i < 4; ++i)
#pragma unroll
    for (int j = 0; j < 4; ++j)
#pragma unroll
      for (int r = 0; r < 4; ++r)
        S[(size_t)(r0 + i * 16 + r) * SEQ + (c0 + j * 16)] = acc[i][j][r];
}

// ---------------- K3: softmax + exact fixup (v1 — measured best, ~32us) -----
// One wave per row. Stages the fp32 row in LDS; recomputes (exact fp32 dot,
// 64-lane-parallel within each candidate) every entry within BAND of the
// approx max -> corrected max is the TRUE max. Corrections stay in LDS (no
// fences, no global writes). Writes P bf16 in-place into S (row slot).
__global__ __launch_bounds__(256) void softmax_fixup(
    float* __restrict__ S, const bf16* __restrict__ qh,
    const bf16* __restrict__ ql, const bf16* __restrict__ kh,
    const bf16* __restrict__ kl) {
  __shared__ __align__(16) float rb[4][4096];
  const int wid = threadIdx.x >> 6;
  const int lane = threadIdx.x & 63;
  const int row = blockIdx.x * 4 + wid;
  const int len = row + 1;
  const int ext = ((row >> 7) + 1) << 7;
  float* srow = S + (size_t)row * SEQ;
  float* rbw = rb[wid];

  // pass A: stage row, approx max
  float m0 = -3.0e38f;
  for (int j = lane * 4; j < len; j += 256) {
    float4 v = *(const float4*)(srow + j);
    *(float4*)&rbw[j] = v;
    if (j + 0 < len) m0 = fmaxf(m0, v.x);
    if (j + 1 < len) m0 = fmaxf(m0, v.y);
    if (j + 2 < len) m0 = fmaxf(m0, v.z);
    if (j + 3 < len) m0 = fmaxf(m0, v.w);
  }
#pragma unroll
  for (int o = 32; o > 0; o >>= 1) m0 = fmaxf(m0, __shfl_xor(m0, o));
  __syncthreads();

  // preload q_row (fp32 reconstruction, 16 elems/lane)
  float q[16];
  {
    const size_t base = (size_t)row * DQK + lane * 16;
    bf16x8 h0 = *(const bf16x8*)(qh + base);
    bf16x8 h1 = *(const bf16x8*)(qh + base + 8);
    bf16x8 l0 = *(const bf16x8*)(ql + base);
    bf16x8 l1 = *(const bf16x8*)(ql + base + 8);
#pragma unroll
    for (int t = 0; t < 8; ++t) {
      q[t] = (float)h0[t] + (float)l0[t];
      q[8 + t] = (float)h1[t] + (float)l1[t];
    }
  }

  // pass B: candidates within BAND of approx max -> exact recompute
  const float T = m0 - 1024.0f;  // band: 640 needed + ~200 error + margin
  float m = -3.0e38f;            // corrected max == TRUE row max
  for (int base = 0; base < len; base += 64) {
    const int j = base + lane;
    const bool cand = (j < len) && (rbw[j] >= T);
    unsigned long long mask = __ballot(cand);
    while (mask) {
      const int jj = base + (int)__builtin_ctzll(mask);
      mask &= mask - 1;
      const size_t kb = (size_t)jj * DQK + lane * 16;
      bf16x8 h0 = *(const bf16x8*)(kh + kb);
      bf16x8 h1 = *(const bf16x8*)(kh + kb + 8);
      bf16x8 l0 = *(const bf16x8*)(kl + kb);
      bf16x8 l1 = *(const bf16x8*)(kl + kb + 8);
      float d = 0.f;
#pragma unroll
      for (int t = 0; t < 8; ++t) {
        d += q[t] * ((float)h0[t] + (float)l0[t]);
        d += q[8 + t] * ((float)h1[t] + (float)l1[t]);
      }
#pragma unroll
      for (int o = 32; o > 0; o >>= 1) d += __shfl_xor(d, o);
      if (lane == 0) rbw[jj] = d;
      m = fmaxf(m, d);
    }
  }
  __syncthreads();

  // pass C: e = exp((s-m)/32) into LDS, sum
  float lsum = 0.f;
  for (int j = lane * 4; j < len; j += 256) {
    float4 v = *(float4*)&rbw[j];
    float4 e;
    e.x = (j + 0 < len) ? __expf((v.x - m) * 0.03125f) : 0.f;
    e.y = (j + 1 < len) ? __expf((v.y - m) * 0.03125f) : 0.f;
    e.z = (j + 2 < len) ? __expf((v.z - m) * 0.03125f) : 0.f;
    e.w = (j + 3 < len) ? __expf((v.w - m) * 0.03125f) : 0.f;
    *(float4*)&rbw[j] = e;
    lsum += e.x + e.y + e.z + e.w;
  }
#pragma unroll
  for (int o = 32; o > 0; o >>= 1) lsum += __shfl_xor(lsum, o);
  const float inv = 1.0f / lsum;
  __syncthreads();

  // pass D: write P bf16 in place (row-owned slot), zero-fill to ext
  bf16* prow = (bf16*)srow;
  for (int j = lane * 8; j < ext; j += 512) {
    bf16x8 o8;
#pragma unroll
    for (int t = 0; t < 8; ++t) {
      const int jj = j + t;
      const float v = (jj < len) ? rbw[jj] * inv : 0.f;
      o8[t] = (bf16)v;
    }
    *(bf16x8*)(prow + j) = o8;
  }
}

// ---------------- K4: O = P V, balanced split-K over causal extent ----------
__global__ __launch_bounds__(256, 2) void pv_kernel(const bf16* __restrict__ P,
                                                    const bf16* __restrict__ vt,
                                                    float* __restrict__ out,
                                                    float* __restrict__ part) {
  __shared__ bf16 sA[128 * 32];
  __shared__ bf16 sB[128 * 32];
  const int g = blockIdx.x >> 3;
  const int bn = blockIdx.x & 7;
  int bm, slice;
  if (g < 8) {
    bm = g;
    slice = 0;
  } else if (g < 24) {
    const int i = g - 8;
    bm = 8 + (i >> 1);
    slice = i & 1;
  } else if (g < 48) {
    const int i = g - 24;
    bm = 16 + i / 3;
    slice = i % 3;
  } else {
    const int i = g - 48;
    bm = 24 + (i >> 2);
    slice = i & 3;
  }
  const int ks0 = slice * 32;
  const int kend = (bm + 1) * 4;
  const int nk = (ks0 + 32 < kend) ? ks0 + 32 : kend;

  const int wid = threadIdx.x >> 6;
  const int lane = threadIdx.x & 63;
  const int wr = (wid >> 1) * 64;
  const int wc = (wid & 1) * 64;

  f32x4 acc[4][4];
#pragma unroll
  for (int i = 0; i < 4; ++i)
#pragma unroll
    for (int j = 0; j < 4; ++j) acc[i][j] = (f32x4)(0.0f);

  for (int kt = ks0; kt < nk; ++kt) {
    const int k0 = kt * 32;
    __syncthreads();
    stage_tile(P, 2 * SEQ, bm * 128, k0, sA, wid, lane);  // ld = 8192
    stage_tile(vt, SEQ, bn * 128, k0, sB, wid, lane);
    __syncthreads();
    bf16x8 a[4], b[4];
#pragma unroll
    for (int i = 0; i < 4; ++i) a[i] = ldsfrag(sA, wr + i * 16, lane);
#pragma unroll
    for (int j = 0; j < 4; ++j) b[j] = ldsfrag(sB, wc + j * 16, lane);
#pragma unroll
    for (int i = 0; i < 4; ++i)
#pragma unroll
      for (int j = 0; j < 4; ++j)
        acc[i][j] = __builtin_amdgcn_mfma_f32_16x16x32_bf16(a[i], b[j],
                                                            acc[i][j], 0, 0, 0);
  }

  float* dst;
  int rbase;
  if (slice == 0) {
    dst = out;
    rbase = 0;
  } else if (slice == 1) {
    dst = part;
    rbase = 1024;
  } else if (slice == 2) {
    dst = part + 3145728;
    rbase = 2048;
  } else {
    dst = part + 5242880;
    rbase = 3072;
  }
  const int r0 = bm * 128 + wr + ((lane >> 4) * 4);
  const int c0 = bn * 128 + wc + (lane & 15);
#pragma unroll
  for (int i = 0; i < 4; ++i)
#pragma unroll
    for (int j = 0; j < 4; ++j)
#pragma unroll
      for (int r = 0; r < 4; ++r)
        dst[(size_t)(r0 + i * 16 + r - rbase) * DV + (c0 + j * 16)] =
            acc[i][j][r];
}

// ---------------- K5: add split-K partial slices into out -------------------
__global__ __launch_bounds__(256) void pv_reduce(const float* __restrict__ part,
                                                 float* __restrict__ out) {
  const int idx = blockIdx.x * 256 + threadIdx.x;
  const int r = 1024 + (idx >> 8);
  const int c4 = (idx & 255) * 4;
  const size_t o = (size_t)r * DV + c4;
  float4 acc = *(float4*)&out[o];
  const float4 p1 = *(const float4*)&part[(size_t)(r - 1024) * DV + c4];
  acc.x += p1.x; acc.y += p1.y; acc.z += p1.z; acc.w += p1.w;
  if (r >= 2048) {
    const float4 p2 =
        *(const float4*)&part[3145728 + (size_t)(r - 2048) * DV + c4];
    acc.x += p2.x; acc.y += p2.y; acc.z += p2.z; acc.w += p2.w;
  }
  if (r >= 3072) {
    const float4 p3 =
        *(const float4*)&part[5242880 + (size_t)(r - 3072) * DV + c4];
    acc.x += p3.x; acc.y += p3.y; acc.z += p3.z; acc.w += p3.w;
  }
  *(float4*)&out[o] = acc;
}

// ---------------- launch ----------------
extern "C" void kernel_launch(void* const* d_in, const int* in_sizes, int n_in,
                              void* d_out, int out_size, void* d_ws,
                              size_t ws_size, hipStream_t stream) {
  const float* x = (const float*)d_in[0];
  const float* Wq = (const float*)d_in[1];
  const float* Wk = (const float*)d_in[2];
  const float* Wv = (const float*)d_in[3];
  float* out = (float*)d_out;
  char* ws = (char*)d_ws;

  const size_t MB = 1024 * 1024;
  const size_t OFF_QH = 0, OFF_QL = 8 * MB, OFF_KH = 16 * MB, OFF_KL = 24 * MB;
  const size_t OFF_PART = 0;  // 24 MB fp32 tight-packed (aliases dead Q/K)
  const size_t OFF_VT = 32 * MB;
  const size_t OFF_S = 40 * MB;
  const size_t OFF_XH = 40 * MB, OFF_XL = 48 * MB;
  const size_t OFF_WQH = 56 * MB, OFF_WQL = 58 * MB;
  const size_t OFF_WKH = 60 * MB, OFF_WKL = 62 * MB, OFF_WVT = 64 * MB;
  const size_t NEEDED = 104 * MB;
  if (ws_size < NEEDED) return;

  bf16* qh = (bf16*)(ws + OFF_QH);
  bf16* ql = (bf16*)(ws + OFF_QL);
  bf16* kh = (bf16*)(ws + OFF_KH);
  bf16* kl = (bf16*)(ws + OFF_KL);
  float* part = (float*)(ws + OFF_PART);
  bf16* vt = (bf16*)(ws + OFF_VT);
  float* S = (float*)(ws + OFF_S);
  bf16* xh = (bf16*)(ws + OFF_XH);
  bf16* xl = (bf16*)(ws + OFF_XL);
  bf16* wqh = (bf16*)(ws + OFF_WQH);
  bf16* wql = (bf16*)(ws + OFF_WQL);
  bf16* wkh = (bf16*)(ws + OFF_WKH);
  bf16* wkl = (bf16*)(ws + OFF_WKL);
  bf16* wvt = (bf16*)(ws + OFF_WVT);

  // K0: conversions
  split_f32<<<(SEQ * DIN / 4 + 255) / 256, 256, 0, stream>>>(x, xh, xl,
                                                             SEQ * DIN / 4);
  wtrans_all<<<3072, 256, 0, stream>>>(Wq, Wk, Wv, wqh, wql, wkh, wkl, wvt);

  // K1: fused projections (Q split, K split, V^T plain) — 768 blocks
  fused_proj<<<768, 256, 0, stream>>>(xh, xl, wqh, wql, wkh, wkl, wvt, qh, ql,
                                      kh, kl, vt);

  // K2: causal scores, single bf16 pass -> S fp32
  score1<<<(SEQ / 128) * (SEQ / 128 + 1) / 2, 256, 0, stream>>>(qh, kh, S);

  // K3: softmax with exact near-max fixup; writes P bf16 in-place into S
  softmax_fixup<<<SEQ / 4, 256, 0, stream>>>(S, qh, ql, kh, kl);

  // K4: O = P V, balanced split-K (640 blocks)
  pv_kernel<<<640, 256, 0, stream>>>((const bf16*)S, vt, out, part);

  // K5: fold partial slices into out (rows >= 1024)
  pv_reduce<<<(SEQ - 1024) * DV / 4 / 256, 256, 0, stream>>>(part, out);
}